// Round 2
// baseline (271.535 us; speedup 1.0000x reference)
//
#include <hip/hip_runtime.h>

// Sparse 2:4 grouped conv, MI355X.  R4 (resubmit — prior round hit a GPU
// acquisition timeout, never measured): pipelined conv — double-buffered LDS,
// prefetch stage s+1 before computing stage s, ONE barrier per stage (its
// implicit vmcnt(0) drain lands after the MFMAs, hiding load latency under
// compute).  Prep kernel unchanged from R3.

#define INF   1152
#define HO    56
#define LOUT  3136      // 56*56
#define XP    58        // padded spatial

typedef __attribute__((ext_vector_type(8))) short bf16x8;
typedef __attribute__((ext_vector_type(4))) float f32x4;

__device__ __forceinline__ unsigned short f2bf(float f) {
  union { float f; unsigned u; } v; v.f = f;
  unsigned r = v.u + 0x7fffu + ((v.u >> 16) & 1u);   // RNE
  return (unsigned short)(r >> 16);
}

__device__ __forceinline__ void async_load16(const void* g, void* l) {
  __builtin_amdgcn_global_load_lds(
      (const __attribute__((address_space(1))) void*)g,
      (__attribute__((address_space(3))) void*)l, 16, 0, 0);
}

// ---------------- fused prep: pad+transpose+cast x  |  gumbel+mask+pack W ------
// blocks [0,3712): xpose (bg=bid/58, ihp=bid%58)
// blocks [3712,4864): Wt[g][tap][of][c] pack with inline gumbel argmax
__global__ __launch_bounds__(256) void prep_kernel(
    const float* __restrict__ x, const float* __restrict__ Ws,
    const float* __restrict__ cw, const float* __restrict__ gb,
    const float* __restrict__ pat,
    unsigned short* __restrict__ Xt, unsigned short* __restrict__ Wt) {
  __shared__ float lds[56 * 129];
  const int t   = threadIdx.x;
  const int bid = blockIdx.x;

  if (bid >= 3712) {                                 // ---- weight pack ----
    int idx = (bid - 3712) * 256 + t;                // 294912 total
    int c   = idx & 127;
    int of  = (idx >> 7) & 127;
    int gt  = idx >> 14;                             // g*9+tap
    int g   = gt / 9;
    int tap = gt - g * 9;
    int e   = ((g << 7) + of) * INF + c * 9 + tap;
    int q   = e >> 2, pos = e & 3;
    const float* cq = cw + q * 6;
    const float* gq = gb + q * 6;
    float best = cq[0] + gq[0]; int bi = 0;
    #pragma unroll
    for (int j = 1; j < 6; ++j) {
      float v2 = cq[j] + gq[j];
      if (v2 > best) { best = v2; bi = j; }          // strict > = first-max
    }
    Wt[idx] = f2bf(Ws[e] * pat[bi * 4 + pos]);
    return;
  }

  // ---- xpose: x (B,256,56,56) f32 -> Xt[bg][58][58][c=128] bf16, zero borders
  const int bg  = bid / 58;
  const int ihp = bid - bg * 58;
  uint4* dst = (uint4*)(Xt + ((bg * XP + ihp) * XP) * 128);
  if (ihp == 0 || ihp == XP - 1) {
    const uint4 z = {0u, 0u, 0u, 0u};
    for (int i = t; i < XP * 16; i += 256) dst[i] = z;
    return;
  }
  const int ih = ihp - 1;
  const float4* src = (const float4*)(x + (bg * 128) * LOUT + ih * HO);
  for (int i = t; i < 128 * 14; i += 256) {
    int c = i / 14, seg = i - c * 14;                // iw = seg*4
    float4 v = src[c * (LOUT / 4) + seg];
    float* row = &lds[(seg * 4) * 129 + c];
    row[0]       = v.x;
    row[129]     = v.y;
    row[2 * 129] = v.z;
    row[3 * 129] = v.w;
  }
  __syncthreads();
  for (int i = t; i < XP * 16; i += 256) {
    int iwp = i >> 4, oct = i & 15;
    uint4 val = {0u, 0u, 0u, 0u};
    if (iwp != 0 && iwp != XP - 1) {
      const float* s = &lds[(iwp - 1) * 129 + (oct << 3)];
      val.x = (unsigned)f2bf(s[0]) | ((unsigned)f2bf(s[1]) << 16);
      val.y = (unsigned)f2bf(s[2]) | ((unsigned)f2bf(s[3]) << 16);
      val.z = (unsigned)f2bf(s[4]) | ((unsigned)f2bf(s[5]) << 16);
      val.w = (unsigned)f2bf(s[6]) | ((unsigned)f2bf(s[7]) << 16);
    }
    dst[i] = val;
  }
}

// ---------------- conv: implicit-GEMM, BK=64, xor-swizzled LDS, dbuf pipeline --
// LDS row = 64 c = 8 chunks of 16B; chunk (row,ch) stored at slot ch^(row&7).
// Staging: wave issue covers 8 rows x 8 chunks = 1 KB; lane l -> row +(l>>3),
// logical ch (l&7)^(l>>3)  (matches lane-linear LDS dest constraint).
// Pipeline: stage s lives in buf[s&1]; iter s issues stage s+1 into buf[s&1^1],
// computes buf[s&1], then ONE __syncthreads() (implicit vmcnt(0)+lgkmcnt(0)
// drain AFTER the MFMAs).  Race-free: buf[n] is rewritten at iter s+1 only
// after the iter-s barrier proved all waves' ds_reads of buf[n] completed.
__global__ __launch_bounds__(256, 2) void conv_mfma_kernel(
    const unsigned short* __restrict__ Wt, const unsigned short* __restrict__ Xt,
    float* __restrict__ out) {
  __shared__ __align__(16) unsigned short sA[2][128 * 64];   // 2 x 16 KB
  __shared__ __align__(16) unsigned short sB[2][128 * 64];   // 2 x 16 KB
  const int t  = threadIdx.x;
  const int ln = t & 63, wv = t >> 6;
  const int wm = wv >> 1, wn = wv & 1;
  const int col = ln & 15, kq = ln >> 4, c7 = col & 7;

  // XCD-aware swizzle: contiguous bg range per XCD for L2 locality
  const int lid   = blockIdx.y * 25 + blockIdx.x;
  const int v     = (lid & 7) * 200 + (lid >> 3);
  const int bg    = v / 25;
  const int tileN = v - bg * 25;
  const int g     = bg & 1;
  const int l0    = tileN << 7;

  // staging geometry (fixed per thread)
  const int r8 = ln >> 3;                  // row within 8-row issue group
  const int ch = (ln & 7) ^ r8;            // logical 16B chunk within 64-c row
  int arow[4], brow[4];
  #pragma unroll
  for (int i = 0; i < 4; ++i) {
    const int rr = (wv << 5) + (i << 3) + r8;      // 0..127
    arow[i] = (rr << 7) + (ch << 3);               // of*128 + c
    int ll = l0 + rr;
    if (ll > LOUT - 1) ll = LOUT - 1;              // tail tile: clamp
    int oh = ll / HO, ow = ll - oh * HO;
    brow[i] = ((bg * XP + oh) * XP + ow) * 128 + (ch << 3);
  }

  f32x4 acc[4][4];
  #pragma unroll
  for (int i = 0; i < 4; ++i)
    #pragma unroll
    for (int j = 0; j < 4; ++j) acc[i][j] = (f32x4){0.f, 0.f, 0.f, 0.f};

  // stage s: tap = s>>1, kc = s&1  (tap-major keeps the L2 tap-to-tap reuse)
  auto issue = [&](int s, int nxt) {
    const int tap = s >> 1, kc = s & 1;
    const int th  = (tap * 11) >> 5;               // tap/3 for tap in [0,9)
    const int tw  = tap - th * 3;
    const int bOff = ((th * XP + tw) << 7) + (kc << 6);
    const int aOff = ((g * 9 + tap) << 14) + (kc << 6);
    #pragma unroll
    for (int i = 0; i < 4; ++i) {
      const int lb = ((wv << 5) + (i << 3)) << 6;   // LDS elem base
      async_load16(Wt + aOff + arow[i], &sA[nxt][lb]);
      async_load16(Xt + bOff + brow[i], &sB[nxt][lb]);
    }
  };

  issue(0, 0);
  __syncthreads();                                 // drain stage-0 loads

  #pragma unroll 2
  for (int s = 0; s < 18; ++s) {
    const int cur = s & 1;
    if (s < 17) issue(s + 1, cur ^ 1);             // prefetch next stage
    #pragma unroll
    for (int kh = 0; kh < 2; ++kh) {
      const int pk = (((kh << 2) + kq) ^ c7) << 3;   // swizzled chunk offset
      bf16x8 af[4], bfr[4];
      #pragma unroll
      for (int mi = 0; mi < 4; ++mi)
        af[mi] = *(const bf16x8*)&sA[cur][(((wm << 6) + (mi << 4) + col) << 6) + pk];
      #pragma unroll
      for (int ni = 0; ni < 4; ++ni)
        bfr[ni] = *(const bf16x8*)&sB[cur][(((wn << 6) + (ni << 4) + col) << 6) + pk];
      #pragma unroll
      for (int mi = 0; mi < 4; ++mi)
        #pragma unroll
        for (int ni = 0; ni < 4; ++ni)
          acc[mi][ni] = __builtin_amdgcn_mfma_f32_16x16x32_bf16(
              af[mi], bfr[ni], acc[mi][ni], 0, 0, 0);
    }
    __syncthreads();     // implicit vmcnt(0): next stage's loads land here,
  }                      // AFTER this stage's MFMAs — latency hidden

  // epilogue: C/D layout col=lane&15, row=(lane>>4)*4+reg
  const int rowq = kq << 2;
  #pragma unroll
  for (int mi = 0; mi < 4; ++mi) {
    #pragma unroll
    for (int ni = 0; ni < 4; ++ni) {
      const int l = l0 + (wn << 6) + (ni << 4) + col;
      if (l < LOUT) {
        #pragma unroll
        for (int r = 0; r < 4; ++r) {
          const int of = (wm << 6) + (mi << 4) + rowq + r;
          out[(bg * 128 + of) * LOUT + l] = acc[mi][ni][r];
        }
      }
    }
  }
}

extern "C" void kernel_launch(void* const* d_in, const int* in_sizes, int n_in,
                              void* d_out, int out_size, void* d_ws, size_t ws_size,
                              hipStream_t stream) {
  const float* x   = (const float*)d_in[0];
  const float* Ws  = (const float*)d_in[1];
  const float* cw  = (const float*)d_in[2];
  const float* gb  = (const float*)d_in[3];
  const float* pat = (const float*)d_in[4];
  float* out = (float*)d_out;

  unsigned short* Wt = (unsigned short*)d_ws;                       // 576 KB
  unsigned short* Xt = (unsigned short*)((char*)d_ws + (1 << 20));  // 52.6 MB

  prep_kernel<<<4864, 256, 0, stream>>>(x, Ws, cw, gb, pat, Xt, Wt);
  conv_mfma_kernel<<<dim3(25, 64), 256, 0, stream>>>(Wt, Xt, out);
}

// Round 3
// 261.370 us; speedup vs baseline: 1.0389x; 1.0389x over previous
//
#include <hip/hip_runtime.h>

// Sparse 2:4 grouped conv, MI355X.  R5: hoist B staging out of the tap loop.
// Post-mortem R4: stage-level staging BW (32 KB/block/stage ≈ 1200 cyc) >>
// MFMA (≈300 cyc) — pipelining can't hide it; must shrink staged bytes.
// R5: per kc half, stage the block's whole input region ONCE (6 rows x 64
// cols x 64 c = 48 KB, position-XOR-swizzled); 9 taps then read it in place
// and stage only the 16 KB A-slice (double-buffered, 1 barrier/tap).
// Staged bytes/block 576 -> 384 KB; per-tap staging 32 -> 16 KB < MFMA time.

#define INF   1152
#define HO    56
#define LOUT  3136      // 56*56
#define XP    58        // padded spatial

typedef __attribute__((ext_vector_type(8))) short bf16x8;
typedef __attribute__((ext_vector_type(4))) float f32x4;

__device__ __forceinline__ unsigned short f2bf(float f) {
  union { float f; unsigned u; } v; v.f = f;
  unsigned r = v.u + 0x7fffu + ((v.u >> 16) & 1u);   // RNE
  return (unsigned short)(r >> 16);
}

__device__ __forceinline__ void async_load16(const void* g, void* l) {
  __builtin_amdgcn_global_load_lds(
      (const __attribute__((address_space(1))) void*)g,
      (__attribute__((address_space(3))) void*)l, 16, 0, 0);
}

// ---------------- fused prep: pad+transpose+cast x  |  gumbel+mask+pack W ------
// (unchanged from R3)
__global__ __launch_bounds__(256) void prep_kernel(
    const float* __restrict__ x, const float* __restrict__ Ws,
    const float* __restrict__ cw, const float* __restrict__ gb,
    const float* __restrict__ pat,
    unsigned short* __restrict__ Xt, unsigned short* __restrict__ Wt) {
  __shared__ float lds[56 * 129];
  const int t   = threadIdx.x;
  const int bid = blockIdx.x;

  if (bid >= 3712) {                                 // ---- weight pack ----
    int idx = (bid - 3712) * 256 + t;                // 294912 total
    int c   = idx & 127;
    int of  = (idx >> 7) & 127;
    int gt  = idx >> 14;                             // g*9+tap
    int g   = gt / 9;
    int tap = gt - g * 9;
    int e   = ((g << 7) + of) * INF + c * 9 + tap;
    int q   = e >> 2, pos = e & 3;
    const float* cq = cw + q * 6;
    const float* gq = gb + q * 6;
    float best = cq[0] + gq[0]; int bi = 0;
    #pragma unroll
    for (int j = 1; j < 6; ++j) {
      float v2 = cq[j] + gq[j];
      if (v2 > best) { best = v2; bi = j; }          // strict > = first-max
    }
    Wt[idx] = f2bf(Ws[e] * pat[bi * 4 + pos]);
    return;
  }

  // ---- xpose: x (B,256,56,56) f32 -> Xt[bg][58][58][c=128] bf16, zero borders
  const int bg  = bid / 58;
  const int ihp = bid - bg * 58;
  uint4* dst = (uint4*)(Xt + ((bg * XP + ihp) * XP) * 128);
  if (ihp == 0 || ihp == XP - 1) {
    const uint4 z = {0u, 0u, 0u, 0u};
    for (int i = t; i < XP * 16; i += 256) dst[i] = z;
    return;
  }
  const int ih = ihp - 1;
  const float4* src = (const float4*)(x + (bg * 128) * LOUT + ih * HO);
  for (int i = t; i < 128 * 14; i += 256) {
    int c = i / 14, seg = i - c * 14;                // iw = seg*4
    float4 v = src[c * (LOUT / 4) + seg];
    float* row = &lds[(seg * 4) * 129 + c];
    row[0]       = v.x;
    row[129]     = v.y;
    row[2 * 129] = v.z;
    row[3 * 129] = v.w;
  }
  __syncthreads();
  for (int i = t; i < XP * 16; i += 256) {
    int iwp = i >> 4, oct = i & 15;
    uint4 val = {0u, 0u, 0u, 0u};
    if (iwp != 0 && iwp != XP - 1) {
      const float* s = &lds[(iwp - 1) * 129 + (oct << 3)];
      val.x = (unsigned)f2bf(s[0]) | ((unsigned)f2bf(s[1]) << 16);
      val.y = (unsigned)f2bf(s[2]) | ((unsigned)f2bf(s[3]) << 16);
      val.z = (unsigned)f2bf(s[4]) | ((unsigned)f2bf(s[5]) << 16);
      val.w = (unsigned)f2bf(s[6]) | ((unsigned)f2bf(s[7]) << 16);
    }
    dst[i] = val;
  }
}

// ---------------- conv: implicit-GEMM, region-staged B, per-tap A dbuf --------
// LDS: sA[2][128 of][64 c] (2x16 KB, chunk^(row&7) swizzle as before).
//      sB[384 pos][64 c]   (48 KB): pos p = (ihp-oh0)*64 + iwp covers the 6
//      input rows x 58(+6 pad) cols this block's 128 output pixels need for
//      ALL 9 taps.  Chunk slot = chunk ^ (p&7) (pre-swizzled global source,
//      lane-linear LDS dest).  Cols 58..63 / rows past 57 are clamped reads
//      (never consumed).
// Loop: per kc half { stage B region once; 9 taps: stage A(tap+1) 16 KB into
// alternate slot, 32 MFMA from sA[cur]+sB, ONE barrier } — per-tap staging
// (16 KB/block ~ 900 cyc/CU at 2 blocks) < per-tap MFMA (~1240 cyc/CU).
__global__ __launch_bounds__(256, 2) void conv_mfma_kernel(
    const unsigned short* __restrict__ Wt, const unsigned short* __restrict__ Xt,
    float* __restrict__ out) {
  __shared__ __align__(16) unsigned short sA[2][128 * 64];   // 32 KB
  __shared__ __align__(16) unsigned short sB[384 * 64];      // 48 KB
  const int t  = threadIdx.x;
  const int ln = t & 63, wv = t >> 6;
  const int wm = wv >> 1, wn = wv & 1;
  const int col = ln & 15, kq = ln >> 4, c7 = col & 7;

  // XCD-aware swizzle: contiguous bg range per XCD for L2 locality
  const int lid   = blockIdx.y * 25 + blockIdx.x;
  const int v     = (lid & 7) * 200 + (lid >> 3);
  const int bg    = v / 25;
  const int tileN = v - bg * 25;
  const int g     = bg & 1;
  const int l0    = tileN << 7;
  const int oh0   = l0 / HO;                 // first output row of tile

  // ---- A staging geometry (unchanged): 4 loads/thread per (kc,tap)
  const int r8 = ln >> 3;
  const int ch = (ln & 7) ^ r8;              // pre-swizzled source chunk
  int arow[4];
  #pragma unroll
  for (int i = 0; i < 4; ++i)
    arow[i] = (((wv << 5) + (i << 3) + r8) << 7) + (ch << 3);

  // ---- B region staging geometry: 12 loads/thread per kc
  const int p0    = t >> 3;                  // 0..31 (position within group)
  const int kB    = (t & 7) ^ (p0 & 7);      // pre-swizzled source chunk
  const int xbase = bg * (XP * XP * 128);

  // ---- B read geometry: per-lane position base per ni
  int pb[4];
  #pragma unroll
  for (int ni = 0; ni < 4; ++ni) {
    int l = l0 + (wn << 6) + (ni << 4) + col;
    if (l > LOUT - 1) l = LOUT - 1;
    int oh = l / HO, ow = l - oh * HO;
    pb[ni] = ((oh - oh0) << 6) + ow;         // region position (tap 0,0)
  }

  // ---- A read offsets (elem), kh=1 via ^32
  int aoffm[4];
  #pragma unroll
  for (int mi = 0; mi < 4; ++mi)
    aoffm[mi] = (((wm << 6) + (mi << 4) + col) << 6) + ((kq ^ c7) << 3);

  f32x4 acc[4][4];
  #pragma unroll
  for (int i = 0; i < 4; ++i)
    #pragma unroll
    for (int j = 0; j < 4; ++j) acc[i][j] = (f32x4){0.f, 0.f, 0.f, 0.f};

  for (int kc = 0; kc < 2; ++kc) {
    const int c0 = kc << 6;
    // stage B region: 384 pos x 8 chunks = 3072 units = 12 rounds x 256 thr
    #pragma unroll
    for (int it = 0; it < 12; ++it) {
      const int p   = (it << 5) + p0;
      int ihp = oh0 + (p >> 6);  if (ihp > XP - 1) ihp = XP - 1;   // clamp
      int iwp = p & 63;          if (iwp > XP - 1) iwp = XP - 1;   // clamp
      async_load16(Xt + xbase + (ihp * XP + iwp) * 128 + c0 + (kB << 3),
                   &sB[(it << 11) + (wv << 9)]);
    }
    // stage A(kc, tap 0) into slot 0
    #pragma unroll
    for (int i = 0; i < 4; ++i)
      async_load16(Wt + (g * 9 << 14) + c0 + arow[i],
                   &sA[0][((wv << 5) + (i << 3)) << 6]);
    __syncthreads();                         // drain region + A0

    for (int tap = 0; tap < 9; ++tap) {
      const int cur = tap & 1;
      if (tap < 8) {                         // prefetch A(tap+1)
        const int aOff = ((g * 9 + tap + 1) << 14) + c0;
        #pragma unroll
        for (int i = 0; i < 4; ++i)
          async_load16(Wt + aOff + arow[i],
                       &sA[cur ^ 1][((wv << 5) + (i << 3)) << 6]);
      }
      const int th = (tap * 11) >> 5;        // tap/3
      const int tw = tap - th * 3;
      int boff[4];
      #pragma unroll
      for (int ni = 0; ni < 4; ++ni) {
        const int p = pb[ni] + (th << 6) + tw;
        boff[ni] = (p << 6) + ((kq ^ (p & 7)) << 3);
      }
      #pragma unroll
      for (int kh = 0; kh < 2; ++kh) {
        const int kx = kh << 5;              // flips chunk bit2 (elem bit5)
        bf16x8 af[4], bfr[4];
        #pragma unroll
        for (int mi = 0; mi < 4; ++mi)
          af[mi] = *(const bf16x8*)&sA[cur][aoffm[mi] ^ kx];
        #pragma unroll
        for (int ni = 0; ni < 4; ++ni)
          bfr[ni] = *(const bf16x8*)&sB[boff[ni] ^ kx];
        #pragma unroll
        for (int mi = 0; mi < 4; ++mi)
          #pragma unroll
          for (int ni = 0; ni < 4; ++ni)
            acc[mi][ni] = __builtin_amdgcn_mfma_f32_16x16x32_bf16(
                af[mi], bfr[ni], acc[mi][ni], 0, 0, 0);
      }
      __syncthreads();   // implicit vmcnt(0): A(tap+1) landed; WAR-safe
    }
  }

  // epilogue: C/D layout col=lane&15, row=(lane>>4)*4+reg
  const int rowq = kq << 2;
  #pragma unroll
  for (int mi = 0; mi < 4; ++mi) {
    #pragma unroll
    for (int ni = 0; ni < 4; ++ni) {
      const int l = l0 + (wn << 6) + (ni << 4) + col;
      if (l < LOUT) {
        #pragma unroll
        for (int r = 0; r < 4; ++r) {
          const int of = (wm << 6) + (mi << 4) + rowq + r;
          out[(bg * 128 + of) * LOUT + l] = acc[mi][ni][r];
        }
      }
    }
  }
}

extern "C" void kernel_launch(void* const* d_in, const int* in_sizes, int n_in,
                              void* d_out, int out_size, void* d_ws, size_t ws_size,
                              hipStream_t stream) {
  const float* x   = (const float*)d_in[0];
  const float* Ws  = (const float*)d_in[1];
  const float* cw  = (const float*)d_in[2];
  const float* gb  = (const float*)d_in[3];
  const float* pat = (const float*)d_in[4];
  float* out = (float*)d_out;

  unsigned short* Wt = (unsigned short*)d_ws;                       // 576 KB
  unsigned short* Xt = (unsigned short*)((char*)d_ws + (1 << 20));  // 55 MB

  prep_kernel<<<4864, 256, 0, stream>>>(x, Ws, cw, gb, pat, Xt, Wt);
  conv_mfma_kernel<<<dim3(25, 64), 256, 0, stream>>>(Wt, Xt, out);
}